// Round 12
// baseline (99.006 us; speedup 1.0000x reference)
//
#include <hip/hip_runtime.h>
#include <hip/hip_bf16.h>
#include <hip/hip_fp16.h>
#include <math.h>

// ---------------------------------------------------------------------------
// HighFreqSuppressionLoss, real-packed rows + Hermitian-halved columns.
// gray = (0.299R+0.587G+0.114B+1)/2; F = fft2(gray);
// loss = mean_b | mean_M log10(|F_gen|^2+eps) - mean_M log10(|F_tgt|^2+eps) |
// Mask excludes (kx,ky) iff lowband(kx)&&lowband(ky); lowband: k<64||k>=448.
//
// FFT core (fft512x): cross-lane, NO LDS exchange. n = 64c + 8a + b with
//   c = reg digit, a = lane>>3, b = lane&7.
//   Step 1: fft8 over regs (digit c) -> k0 = reg m; twiddle w512^{t*k0}.
//   Step 2: 8-pt DFT along digit a = 3 radix-2 DIF stages via shfl_xor
//           (masks 32,16,8), twiddles W8^{a&3}, W4^{a&1} (lane constants).
//   Step 2.5: twiddle w64^{b * br3(a)} (static per lane).
//   Step 3: same along digit b (masks 4,2,1).
//   Result: reg m of lane (pa,pb) = X[m + 8*br3(pa) + 64*br3(pb)]
//   -> each lane's 8 regs are 8 CONTIGUOUS frequencies (2 uint4 stores).
//   Verified analytically on DC and K=8 tones.
// Stage 1: pack rows (2p,2p+1) as z=a+ib; 8 pairs/wave, double-buffered
//   LDS-DMA staging, counted vmcnt (12/14/2, never 0 mid-loop).
//   Z fp16, TRUE frequency order: ws[img][pair][kx].
// Stage 2: 16 columns/block, kx=0..256 (Hermitian PSD symmetry);
//   element weight base=(kx==0||kx==256)?1:2, minus [kx<=63]*[ky in S],
//   minus [1<=kx<=64]*[ky in S'];
//   ky digits: v=br3(pb), u=br3(pa), ky = m + 8u + 64v.
//   S  (ky<64 | ky>=448)  <=> pb==0 | pb==7            (lane-uniform)
//   S' (ky<=64 | ky>=449) <=> pb==0 | (pb==4&pa==0&m==0)
//                                   | (pb==7 & !(pa==0&m==0))
//   (weight totals 245760, matches passing R4-R11 math)
// ---------------------------------------------------------------------------

__device__ double g_partials[64 * 17 * 4];                   // [img][blk][wave]
__device__ __align__(16) __half2 g_ws[(size_t)64 * 256 * 512];  // 32 MiB

__device__ __forceinline__ float2 cadd(float2 a, float2 b){ return make_float2(a.x+b.x, a.y+b.y); }
__device__ __forceinline__ float2 csub(float2 a, float2 b){ return make_float2(a.x-b.x, a.y-b.y); }
__device__ __forceinline__ float2 cmul(float2 a, float2 b){
  return make_float2(fmaf(a.x, b.x, -(a.y*b.y)), fmaf(a.x, b.y, a.y*b.x));
}
__device__ __forceinline__ float2 mul_mi(float2 a){ return make_float2(a.y, -a.x); } // *(-i)
__device__ __forceinline__ int br3(int x){ return ((x&1)<<2) | (x&2) | ((x>>2)&1); }

__device__ __forceinline__ void fft8(float2 v[8]){
  const float S = 0.70710678118654752440f;
  float2 c0=cadd(v[0],v[4]), c1=cadd(v[1],v[5]), c2=cadd(v[2],v[6]), c3=cadd(v[3],v[7]);
  float2 d0=csub(v[0],v[4]);
  float2 t1=csub(v[1],v[5]);
  float2 d1=make_float2(S*(t1.x+t1.y), S*(t1.y-t1.x));   // *w8^1
  float2 d2=mul_mi(csub(v[2],v[6]));                     // *w8^2
  float2 t3=csub(v[3],v[7]);
  float2 d3=make_float2(S*(t3.y-t3.x), -S*(t3.x+t3.y));  // *w8^3
  float2 e0=cadd(c0,c2), e1=cadd(c1,c3), f0=csub(c0,c2), f1=mul_mi(csub(c1,c3));
  float2 g0=cadd(d0,d2), g1=cadd(d1,d3), h0=csub(d0,d2), h1=mul_mi(csub(d1,d3));
  v[0]=cadd(e0,e1); v[4]=csub(e0,e1);
  v[2]=cadd(f0,f1); v[6]=csub(f0,f1);
  v[1]=cadd(g0,g1); v[5]=csub(g0,g1);
  v[3]=cadd(h0,h1); v[7]=csub(h0,h1);
}

__device__ __forceinline__ float2 shflx(float2 x, int m){
  return make_float2(__shfl_xor(x.x, m, 64), __shfl_xor(x.y, m, 64));
}

// Radix-2 DIF butterfly along lanes, all 8 regs. hi lanes: (u-y)*w; lo: y+u.
__device__ __forceinline__ void bfly(float2 v[8], int maskbit, bool hi, float2 w){
  #pragma unroll
  for (int m = 0; m < 8; ++m){
    float2 u = shflx(v[m], maskbit);
    float2 s = cmul(csub(u, v[m]), w);
    float2 a = cadd(v[m], u);
    v[m] = hi ? s : a;
  }
}
__device__ __forceinline__ void bfly_nw(float2 v[8], int maskbit, bool hi){
  #pragma unroll
  for (int m = 0; m < 8; ++m){
    float2 u = shflx(v[m], maskbit);
    float2 s = csub(u, v[m]);
    float2 a = cadd(v[m], u);
    v[m] = hi ? s : a;
  }
}

// Per-lane twiddle constants (computed once per kernel).
struct LaneTw {
  float2 wp[7];                 // w512^{t*m}, m=1..7
  float2 wA1, wA2, wB1, wB2;    // butterfly twiddles
  float2 w25;                   // w64^{b*br3(a)}
};

__device__ __forceinline__ LaneTw make_lanetw(int t){
  LaneTw L;
  const float TW = -6.28318530717958647692f;
  const float S  = 0.70710678118654752440f;
  float sn, cs;
  __sincosf(TW * (float)t * (1.0f/512.0f), &sn, &cs);
  float2 w1 = make_float2(cs, sn);
  L.wp[0] = w1;
  #pragma unroll
  for (int i = 1; i < 7; ++i) L.wp[i] = cmul(L.wp[i-1], w1);
  const int a = t >> 3, b = t & 7;
  const int ea = a & 3, eb = b & 3;
  // W8^e: 0:(1,0) 1:(S,-S) 2:(0,-1) 3:(-S,-S)
  L.wA1 = make_float2((ea==0)?1.0f:(ea==1)?S:(ea==2)?0.0f:-S,
                      (ea==0)?0.0f:(ea==1)?-S:(ea==2)?-1.0f:-S);
  L.wB1 = make_float2((eb==0)?1.0f:(eb==1)?S:(eb==2)?0.0f:-S,
                      (eb==0)?0.0f:(eb==1)?-S:(eb==2)?-1.0f:-S);
  L.wA2 = (a & 1) ? make_float2(0.0f,-1.0f) : make_float2(1.0f,0.0f);
  L.wB2 = (b & 1) ? make_float2(0.0f,-1.0f) : make_float2(1.0f,0.0f);
  const int k1 = br3(a);
  __sincosf(TW * (float)(b * k1) * (1.0f/64.0f), &sn, &cs);
  L.w25 = make_float2(cs, sn);
  return L;
}

// 512-pt FFT, register + cross-lane. In: v[c] = x[t + 64c].
// Out: reg m of lane t holds X[m + 8*br3(t>>3) + 64*br3(t&7)].
__device__ __forceinline__ void fft512x(float2 v[8], const LaneTw& L, int t){
  fft8(v);
  #pragma unroll
  for (int m = 1; m < 8; ++m) v[m] = cmul(v[m], L.wp[m-1]);
  bfly   (v, 32, (t & 32) != 0, L.wA1);
  bfly   (v, 16, (t & 16) != 0, L.wA2);
  bfly_nw(v, 8,  (t & 8)  != 0);
  #pragma unroll
  for (int m = 0; m < 8; ++m) v[m] = cmul(v[m], L.w25);
  bfly   (v, 4, (t & 4) != 0, L.wB1);
  bfly   (v, 2, (t & 2) != 0, L.wB2);
  bfly_nw(v, 1, (t & 1) != 0);
}

// Wave-internal LDS fence (staging WAR guard; no block barrier needed).
__device__ __forceinline__ void lds_fence(){
  asm volatile("s_waitcnt lgkmcnt(0)" ::: "memory");
  __builtin_amdgcn_sched_barrier(0);
}

#define GRAY1(r,g,b) ((fmaf(0.299f,(r), fmaf(0.587f,(g), 0.114f*(b))) + 1.0f)*0.5f)

// Issue 12 x 1KB direct-to-LDS DMA for one row pair (3 channels x 4 segs).
__device__ __forceinline__ void dma_pair(const float* base, float* st, int t){
  #pragma unroll
  for (int ch = 0; ch < 3; ++ch){
    const float* pb = base + ch * 262144 + 4*t;
    float* lb = st + ch*1024;
    #pragma unroll
    for (int seg = 0; seg < 4; ++seg){
      __builtin_amdgcn_global_load_lds(
        (const __attribute__((address_space(1))) void*)(pb + seg*256),
        (__attribute__((address_space(3))) void*)(lb + seg*256),
        16, 0, 0);
    }
  }
}

// Stage 1: pipelined packed row-pair FFTs. Block 128 = 2 waves; 8 pairs/wave,
// double-buffered staging (24KB/wave). Grid = 64 * 16.
__global__ __launch_bounds__(128)
void k_rowfft(const float* __restrict__ gen, const float* __restrict__ tgt){
  const int wg   = blockIdx.x;
  const int img  = wg >> 4;
  const int bl   = wg & 15;
  const int wave = threadIdx.x >> 6, t = threadIdx.x & 63;
  const int prB  = bl*16 + wave*8;               // first of 8 pairs
  const float* src = (img < 32) ? gen : tgt;
  const float* base0 = src + (size_t)(img & 31) * 786432 + (size_t)prB * 1024;

  __shared__ float stage_all[2][2][3072];        // [wave][buf] 12KB staging
  float* stg0 = stage_all[wave][0];
  float* stg1 = stage_all[wave][1];

  const LaneTw L = make_lanetw(t);
  const int kbase = 8*br3(t >> 3) + 64*br3(t & 7);   // half2 units

  dma_pair(base0, stg0, t);                      // prologue: pair 0 in flight
  #pragma unroll
  for (int n = 0; n < 8; ++n){
    float* stc = (n & 1) ? stg1 : stg0;
    float* stn = (n & 1) ? stg0 : stg1;
    // prior iteration's gray reads of stn must drain before DMA overwrites
    lds_fence();
    if (n < 7) dma_pair(base0 + (size_t)(n+1)*1024, stn, t);
    // wait for DMA(n) (oldest 12).  Younger in flight:
    //   n=0: DMA(1) 12 -> vmcnt(12)
    //   1<=n<=6: stores(n-1) 2 + DMA(n+1) 12 -> vmcnt(14)
    //   n=7: stores(6) 2 -> vmcnt(2)
    if (n == 0)      { asm volatile("s_waitcnt vmcnt(12)" ::: "memory"); }
    else if (n < 7)  { asm volatile("s_waitcnt vmcnt(14)" ::: "memory"); }
    else             { asm volatile("s_waitcnt vmcnt(2)"  ::: "memory"); }
    __builtin_amdgcn_sched_barrier(0);

    // Gray from LDS (stride-1 b32 reads, conflict-free).
    float2 v[8];
    #pragma unroll
    for (int j = 0; j < 8; ++j){
      const int x = t + 64*j;
      v[j] = make_float2(GRAY1(stc[x],     stc[1024+x], stc[2048+x]),
                         GRAY1(stc[512+x], stc[1536+x], stc[2560+x]));
    }
    fft512x(v, L, t);

    // Pack fp16; lane's 8 regs are contiguous frequencies kbase..kbase+7.
    __half2 h[8];
    #pragma unroll
    for (int m = 0; m < 8; ++m) h[m] = __floats2half2_rn(v[m].x, v[m].y);
    uint4* dst = (uint4*)(g_ws + ((size_t)img * 256 + (prB + n)) * 512 + kbase);
    const uint4* hp = (const uint4*)h;
    dst[0] = hp[0];                              // 2 x 1KB-per-wave stores
    dst[1] = hp[1];
  }
}

// Stage 2: column FFTs for kx = 0..256 + masked log10 reduction.
// Blocks g=0..15: 16 cols kx=16g..16g+15 (4 cols/wave serially).
// Block g=16: kx=256 only (wave 0, ci 0). Grid = 64 * 17.
__global__ __launch_bounds__(256)
void k_colfft(){
  const int wg   = blockIdx.x;
  const int img  = wg / 17;
  const int blk  = wg - img * 17;
  const int kx0  = blk * 16;
  const int tid  = threadIdx.x;
  const int wave = tid >> 6, t = tid & 63;
  const int ncols = (blk == 16) ? 1 : 16;

  // raw half2 tiles, pad 258: load-writes <=2-way, col reads broadcast-free
  __shared__ __half2 own[16 * 258], mir[16 * 258];

  const __half2* zb = g_ws + (size_t)img * 131072;  // 256 pairs * 512
  #pragma unroll
  for (int it = 0; it < 16; ++it){
    const int idx = it*256 + tid;                   // 0..4095
    const int p = idx >> 4, e = idx & 15;
    own[e*258 + p] = zb[p*512 + kx0 + e];
    mir[e*258 + p] = zb[p*512 + ((512 - (kx0 + e)) & 511)];
  }
  __syncthreads();

  const LaneTw L = make_lanetw(t);
  const int pa = t >> 3, pb = t & 7;
  const bool inS = (pb == 0) | (pb == 7);           // ky in S, lane-uniform

  double acc = 0.0;
  for (int ci = 0; ci < 4; ++ci){
    const int e = wave*4 + ci;
    if (e < ncols){
      const int kx = kx0 + e;
      const bool sub_own = (kx <= 63);              // lowband(kx), kx in 0..256
      const bool sub_mir = (kx >= 1) & (kx <= 64);  // lowband(512-kx)
      const float wbase = (kx == 0 || kx == 256) ? 1.0f : 2.0f;

      float2 v[8];
      const int u = t >> 1;
      const bool odd = (t & 1);
      #pragma unroll
      for (int j = 0; j < 8; ++j){
        const int p = u + 32*j;
        float2 A = __half22float2(own[e*258 + p]);
        float2 B = __half22float2(mir[e*258 + p]); B.y = -B.y;   // conj
        float2 Fe = make_float2((A.x + B.x)*0.5f, (A.y + B.y)*0.5f);
        float2 Fo = mul_mi(make_float2((A.x - B.x)*0.5f, (A.y - B.y)*0.5f));
        v[j] = odd ? Fo : Fe;
      }
      fft512x(v, L, t);

      #pragma unroll
      for (int m = 0; m < 8; ++m){
        const bool m0 = (m == 0);
        const bool inSp = (pb == 0) | ((pb == 4) & (pa == 0) & m0)
                        | ((pb == 7) & !((pa == 0) & m0));
        float wgt = wbase;
        if (sub_own & inS)  wgt -= 1.0f;
        if (sub_mir & inSp) wgt -= 1.0f;
        float m2 = fmaf(v[m].x, v[m].x, fmaf(v[m].y, v[m].y, 1e-10f));
        acc += (double)wgt * (double)log10f(m2);
      }
    }
  }
  #pragma unroll
  for (int off = 32; off; off >>= 1) acc += __shfl_down(acc, off);
  if (t == 0) g_partials[((size_t)img * 17 + blk) * 4 + wave] = acc;
}

// Final: psd per image, L1 over batch.
__global__ __launch_bounds__(256)
void k_finish(float* __restrict__ out){
  const int tid = threadIdx.x;
  const int img = tid >> 2, part = tid & 3;
  const double* p = g_partials + (size_t)img * 68 + part;
  double s = 0.0;
  for (int k = 0; k < 17; ++k) s += p[4*k];
  __shared__ double sm[256];
  sm[tid] = s;
  __syncthreads();
  if ((tid & 3) == 0){
    double tot = sm[tid] + sm[tid+1] + sm[tid+2] + sm[tid+3];
    sm[tid] = tot * (1.0 / 245760.0);          // psd[img]
  }
  __syncthreads();
  if (tid < 64){
    double dv = (tid < 32) ? fabs(sm[tid*4] - sm[(tid+32)*4]) : 0.0;
    #pragma unroll
    for (int off = 32; off; off >>= 1) dv += __shfl_down(dv, off);
    if (tid == 0) out[0] = (float)(dv * (1.0 / 32.0));
  }
}

extern "C" void kernel_launch(void* const* d_in, const int* in_sizes, int n_in,
                              void* d_out, int out_size, void* d_ws, size_t ws_size,
                              hipStream_t stream){
  (void)in_sizes; (void)n_in; (void)out_size; (void)d_ws; (void)ws_size;
  const float* gen = (const float*)d_in[0];
  const float* tgt = (const float*)d_in[1];
  float* out = (float*)d_out;

  k_rowfft<<<dim3(64 * 16), dim3(128), 0, stream>>>(gen, tgt);
  k_colfft<<<dim3(64 * 17), dim3(256), 0, stream>>>();
  k_finish<<<dim3(1), dim3(256), 0, stream>>>(out);
}

// Round 13
// 70.750 us; speedup vs baseline: 1.3994x; 1.3994x over previous
//
#include <hip/hip_runtime.h>
#include <hip/hip_bf16.h>
#include <hip/hip_fp16.h>
#include <math.h>

// ---------------------------------------------------------------------------
// HighFreqSuppressionLoss, real-packed rows + Hermitian-halved columns.
// gray = (0.299R+0.587G+0.114B+1)/2; F = fft2(gray);
// loss = mean_b | mean_M log10(|F_gen|^2+eps) - mean_M log10(|F_tgt|^2+eps) |
// Mask excludes (kx,ky) iff lowband(kx)&&lowband(ky); lowband: k<64||k>=448.
//
// BEST-KNOWN configuration (R8, 70.5 us) — final revert after R9-R12
// exploration regressed or was neutral:
//  - R9  register-pipeline: RA serialized loads (VGPR 64), −6 us.
//  - R10 fused finish w/ __threadfence: XCD-L2 writeback thrash, −60 us.
//  - R11 fence-thinned exchange: neutral.
//  - R12 shfl-based exchange-free FFT: DS-pipe cost identical, +VALU, −28 us.
//
// Stage 1 (pipelined): pack rows (2p,2p+1) as z = a+ib, one 512-pt FFT/pair.
//   8 pairs/wave, double-buffered LDS-DMA staging (global_load_lds, 12x1KB
//   per pair), counted vmcnt (12/20/8, never 0 mid-loop).  Z stored fp16 in
//   TRUE FREQUENCY ORDER into static 32MB buffer: ws[img][pair][kx],
//   kx = 64j + 8(t&7) + (t>>3).
// Stage 2: 16 columns/block (64B-sector stripe reads, own+mirror), kx=0..256;
//   element weight base=(kx==0||kx==256)?1:2, minus [kx<=63]*[ky in S],
//   minus [1<=kx<=64]*[ky in S']; S <=> j==0||j==7,
//   S' <=> j==0 || (j==1&&t==0) || (j==7&&t!=0). (weights total 245760)
// Stage 3: tiny separate k_finish (psd means + L1).
// ---------------------------------------------------------------------------

__device__ double g_partials[64 * 17 * 4];                   // [img][blk][wave]
__device__ __align__(16) __half2 g_ws[(size_t)64 * 256 * 512];  // 32 MiB

__device__ __forceinline__ float2 cadd(float2 a, float2 b){ return make_float2(a.x+b.x, a.y+b.y); }
__device__ __forceinline__ float2 csub(float2 a, float2 b){ return make_float2(a.x-b.x, a.y-b.y); }
__device__ __forceinline__ float2 cmul(float2 a, float2 b){
  return make_float2(fmaf(a.x, b.x, -(a.y*b.y)), fmaf(a.x, b.y, a.y*b.x));
}
__device__ __forceinline__ float2 mul_mi(float2 a){ return make_float2(a.y, -a.x); } // *(-i)

__device__ __forceinline__ void fft8(float2 v[8]){
  const float S = 0.70710678118654752440f;
  float2 c0=cadd(v[0],v[4]), c1=cadd(v[1],v[5]), c2=cadd(v[2],v[6]), c3=cadd(v[3],v[7]);
  float2 d0=csub(v[0],v[4]);
  float2 t1=csub(v[1],v[5]);
  float2 d1=make_float2(S*(t1.x+t1.y), S*(t1.y-t1.x));   // *w8^1
  float2 d2=mul_mi(csub(v[2],v[6]));                     // *w8^2
  float2 t3=csub(v[3],v[7]);
  float2 d3=make_float2(S*(t3.y-t3.x), -S*(t3.x+t3.y));  // *w8^3
  float2 e0=cadd(c0,c2), e1=cadd(c1,c3), f0=csub(c0,c2), f1=mul_mi(csub(c1,c3));
  float2 g0=cadd(d0,d2), g1=cadd(d1,d3), h0=csub(d0,d2), h1=mul_mi(csub(d1,d3));
  v[0]=cadd(e0,e1); v[4]=csub(e0,e1);
  v[2]=cadd(f0,f1); v[6]=csub(f0,f1);
  v[1]=cadd(g0,g1); v[5]=csub(g0,g1);
  v[3]=cadd(h0,h1); v[7]=csub(h0,h1);
}

__device__ __forceinline__ void twiddle8(float2 v[8], float ang){
  float sn, cs;
  __sincosf(ang, &sn, &cs);
  float2 w = make_float2(cs, sn);
  float2 wp = w;
  v[1] = cmul(v[1], wp);
  #pragma unroll
  for (int m = 2; m < 8; ++m){ wp = cmul(wp, w); v[m] = cmul(v[m], wp); }
}

__device__ __forceinline__ int padi(int i){ return i + (i >> 3); }

// Wave-internal LDS fence (exchange is intra-wave; no block barrier needed).
__device__ __forceinline__ void lds_fence(){
  asm volatile("s_waitcnt lgkmcnt(0)" ::: "memory");
  __builtin_amdgcn_sched_barrier(0);
}

// 512-pt DIF FFT across one wave. Lane t holds x[t+64j] on entry.
// Exit: reg j of lane t = stored s = 8t+j, true freq 64j + 8(t&7) + (t>>3).
__device__ __forceinline__ void fft512(float2 v[8], float* re, float* im, int t){
  const float TW = -6.28318530717958647692f;
  fft8(v);
  twiddle8(v, TW * (float)t * (1.0f/512.0f));
  lds_fence();
  #pragma unroll
  for (int m = 0; m < 8; ++m){ int a = padi(m*64 + t); re[a] = v[m].x; im[a] = v[m].y; }
  lds_fence();
  const int q = t >> 3, n = t & 7;
  #pragma unroll
  for (int j = 0; j < 8; ++j){ int a = padi(q*64 + n + 8*j); v[j].x = re[a]; v[j].y = im[a]; }
  fft8(v);
  twiddle8(v, TW * (float)n * (1.0f/64.0f));
  lds_fence();
  #pragma unroll
  for (int m = 0; m < 8; ++m){ int a = padi(q*64 + m*8 + n); re[a] = v[m].x; im[a] = v[m].y; }
  lds_fence();
  #pragma unroll
  for (int j = 0; j < 8; ++j){ int a = padi(q*64 + n*8 + j); v[j].x = re[a]; v[j].y = im[a]; }
  fft8(v);
}

#define GRAY1(r,g,b) ((fmaf(0.299f,(r), fmaf(0.587f,(g), 0.114f*(b))) + 1.0f)*0.5f)

// Issue 12 x 1KB direct-to-LDS DMA for one row pair (3 channels x 4 segs).
__device__ __forceinline__ void dma_pair(const float* base, float* st, int t){
  #pragma unroll
  for (int ch = 0; ch < 3; ++ch){
    const float* pb = base + ch * 262144 + 4*t;
    float* lb = st + ch*1024;
    #pragma unroll
    for (int seg = 0; seg < 4; ++seg){
      __builtin_amdgcn_global_load_lds(
        (const __attribute__((address_space(1))) void*)(pb + seg*256),
        (__attribute__((address_space(3))) void*)(lb + seg*256),
        16, 0, 0);
    }
  }
}

// Stage 1: pipelined packed row-pair FFTs. Block 128 = 2 waves; 8 pairs/wave,
// double-buffered staging (24KB/wave). Grid = 64 * 16.
__global__ __launch_bounds__(128)
void k_rowfft(const float* __restrict__ gen, const float* __restrict__ tgt){
  const int wg   = blockIdx.x;
  const int img  = wg >> 4;
  const int bl   = wg & 15;
  const int wave = threadIdx.x >> 6, t = threadIdx.x & 63;
  const int prB  = bl*16 + wave*8;               // first of 8 pairs
  const float* src = (img < 32) ? gen : tgt;
  const float* base0 = src + (size_t)(img & 31) * 786432 + (size_t)prB * 1024;

  // [wave][buf] 12KB staging; buf[n&1] holds pair n, reused as FFT exchange
  // (re = [0,576), im = [1024,1600)) after gray is consumed into registers.
  __shared__ float stage_all[2][2][3072];
  float* stg0 = stage_all[wave][0];
  float* stg1 = stage_all[wave][1];

  const int off = 8*(t & 7) + (t >> 3);

  dma_pair(base0, stg0, t);                      // prologue: pair 0 in flight
  #pragma unroll
  for (int n = 0; n < 8; ++n){
    float* stc = (n & 1) ? stg1 : stg0;
    float* stn = (n & 1) ? stg0 : stg1;
    // ensure prior FFT's exchange reads (in stn) are drained before DMA
    lds_fence();
    if (n < 7) dma_pair(base0 + (size_t)(n+1)*1024, stn, t);
    // wait for DMA(n): 12 oldest ops.  Younger in flight:
    //   stores(n-1) x8 (n>=1) + DMA(n+1) x12 (n<7)  -> counted, never 0.
    if (n == 0)      { asm volatile("s_waitcnt vmcnt(12)" ::: "memory"); }
    else if (n < 7)  { asm volatile("s_waitcnt vmcnt(20)" ::: "memory"); }
    else             { asm volatile("s_waitcnt vmcnt(8)"  ::: "memory"); }
    __builtin_amdgcn_sched_barrier(0);

    // Gray from LDS (stride-1 b32 reads, conflict-free).
    float2 v[8];
    #pragma unroll
    for (int j = 0; j < 8; ++j){
      const int x = t + 64*j;
      v[j] = make_float2(GRAY1(stc[x],     stc[1024+x], stc[2048+x]),
                         GRAY1(stc[512+x], stc[1536+x], stc[2560+x]));
    }
    fft512(v, stc, stc + 1024, t);

    // Store fp16, TRUE frequency order: reg j -> kx = 64j + off.
    __half2* dst = g_ws + ((size_t)img * 256 + (prB + n)) * 512;
    #pragma unroll
    for (int j = 0; j < 8; ++j) dst[64*j + off] = __floats2half2_rn(v[j].x, v[j].y);
  }
}

// Stage 2: column FFTs for kx = 0..256 + masked log10 reduction.
// Blocks g=0..15: 16 cols kx=16g..16g+15 (4 cols/wave serially).
// Block g=16: kx=256 only (wave 0, ci 0). Grid = 64 * 17.
// Stripe reads are 64B/row sector-aligned chunks (own and mirror).
__global__ __launch_bounds__(256)
void k_colfft(){
  const int wg   = blockIdx.x;
  const int img  = wg / 17;
  const int blk  = wg - img * 17;
  const int kx0  = blk * 16;
  const int tid  = threadIdx.x;
  const int wave = tid >> 6, t = tid & 63;
  const int ncols = (blk == 16) ? 1 : 16;

  // raw half2 tiles, pad 258: load-writes <=2-way, col reads broadcast-free
  __shared__ __half2 own[16 * 258], mir[16 * 258];
  __shared__ float re_all[4][576], im_all[4][576];
  float* re = re_all[wave];
  float* im = im_all[wave];

  const __half2* zb = g_ws + (size_t)img * 131072;  // 256 pairs * 512
  #pragma unroll
  for (int it = 0; it < 16; ++it){
    const int idx = it*256 + tid;                   // 0..4095
    const int p = idx >> 4, e = idx & 15;
    own[e*258 + p] = zb[p*512 + kx0 + e];
    mir[e*258 + p] = zb[p*512 + ((512 - (kx0 + e)) & 511)];
  }
  __syncthreads();

  double acc = 0.0;
  for (int ci = 0; ci < 4; ++ci){
    const int e = wave*4 + ci;
    if (e < ncols){
      const int kx = kx0 + e;
      const bool sub_own = (kx <= 63);              // lowband(kx), kx in 0..256
      const bool sub_mir = (kx >= 1) & (kx <= 64);  // lowband(512-kx)
      const float base = (kx == 0 || kx == 256) ? 1.0f : 2.0f;

      float2 v[8];
      const int u = t >> 1;
      const bool odd = (t & 1);
      #pragma unroll
      for (int j = 0; j < 8; ++j){
        const int p = u + 32*j;
        float2 A = __half22float2(own[e*258 + p]);
        float2 B = __half22float2(mir[e*258 + p]); B.y = -B.y;   // conj
        float2 Fe = make_float2((A.x + B.x)*0.5f, (A.y + B.y)*0.5f);
        float2 Fo = mul_mi(make_float2((A.x - B.x)*0.5f, (A.y - B.y)*0.5f));
        v[j] = odd ? Fo : Fe;
      }
      fft512(v, re, im, t);

      #pragma unroll
      for (int j = 0; j < 8; ++j){
        const bool inS  = (j == 0) | (j == 7);
        const bool inSp = (j == 0) | ((j == 1) & (t == 0)) | ((j == 7) & (t != 0));
        float wgt = base;
        if (sub_own & inS)  wgt -= 1.0f;
        if (sub_mir & inSp) wgt -= 1.0f;
        float m2 = fmaf(v[j].x, v[j].x, fmaf(v[j].y, v[j].y, 1e-10f));
        acc += (double)wgt * (double)log10f(m2);
      }
    }
  }
  #pragma unroll
  for (int off = 32; off; off >>= 1) acc += __shfl_down(acc, off);
  if (t == 0) g_partials[((size_t)img * 17 + blk) * 4 + wave] = acc;
}

// Final: psd per image, L1 over batch.
__global__ __launch_bounds__(256)
void k_finish(float* __restrict__ out){
  const int tid = threadIdx.x;
  const int img = tid >> 2, part = tid & 3;
  const double* p = g_partials + (size_t)img * 68 + part;
  double s = 0.0;
  for (int k = 0; k < 17; ++k) s += p[4*k];
  __shared__ double sm[256];
  sm[tid] = s;
  __syncthreads();
  if ((tid & 3) == 0){
    double tot = sm[tid] + sm[tid+1] + sm[tid+2] + sm[tid+3];
    sm[tid] = tot * (1.0 / 245760.0);          // psd[img]
  }
  __syncthreads();
  if (tid < 64){
    double dv = (tid < 32) ? fabs(sm[tid*4] - sm[(tid+32)*4]) : 0.0;
    #pragma unroll
    for (int off = 32; off; off >>= 1) dv += __shfl_down(dv, off);
    if (tid == 0) out[0] = (float)(dv * (1.0 / 32.0));
  }
}

extern "C" void kernel_launch(void* const* d_in, const int* in_sizes, int n_in,
                              void* d_out, int out_size, void* d_ws, size_t ws_size,
                              hipStream_t stream){
  (void)in_sizes; (void)n_in; (void)out_size; (void)d_ws; (void)ws_size;
  const float* gen = (const float*)d_in[0];
  const float* tgt = (const float*)d_in[1];
  float* out = (float*)d_out;

  k_rowfft<<<dim3(64 * 16), dim3(128), 0, stream>>>(gen, tgt);
  k_colfft<<<dim3(64 * 17), dim3(256), 0, stream>>>();
  k_finish<<<dim3(1), dim3(256), 0, stream>>>(out);
}